// Round 17
// baseline (10113.066 us; speedup 1.0000x reference)
//
#include <hip/hip_runtime.h>

#define B_ROWS 8192
#define IN_D   1024
#define CODE   4096
#define LAYERS 5
#define TOPK   64
// Model: ref = JAX/XLA:CPU f32 via Eigen threaded contraction.
// kc = min((l1-ksub)/kdiv, 320) & ~7 = 288 (AVX2 traits mr=24,nr=4,l1=32K).
//   K=1024 -> {288,288,288,160}; K=4096 -> {288 x 14, 64}.
// jaxlib wheels: AVX without FMA -> Eigen pmadd = mul THEN add (2 roundings).
// Panels folded by f32 adds ascending. u = t1 +f32 t2. top_k stable (low idx).

__device__ __forceinline__ int panel4096(int c) { return c / 288; }

__device__ __forceinline__ float muladd(float a, float b, float acc) {
  return __fadd_rn(acc, __fmul_rn(a, b));   // never contracted to FMA
}

// ---------- dictionary transpose: [1024][4096] -> [4096][1024] ----------
__global__ __launch_bounds__(256) void k_transpose(const float* __restrict__ in,
                                                   float* __restrict__ out) {
  __shared__ float tile[32][33];
  int bx = blockIdx.x, by = blockIdx.y;
  int tx = threadIdx.x, ty = threadIdx.y;  // block (32, 8)
  int x = bx * 32 + tx;
#pragma unroll
  for (int i = 0; i < 4; ++i) {
    int y = by * 32 + ty + i * 8;
    tile[ty + i * 8][tx] = in[(size_t)y * CODE + x];
  }
  __syncthreads();
  int xo = by * 32 + tx;
#pragma unroll
  for (int i = 0; i < 4; ++i) {
    int yo = bx * 32 + ty + i * 8;
    out[(size_t)yo * IN_D + xo] = tile[tx][ty + i * 8];
  }
}

// ---------- t1 = f32 kc=288 panel-chain GEMM, mul+add (no FMA) ----------
#define BM 128
#define BN 128
#define BK 32

__global__ __launch_bounds__(256) void k_gemm_np(const float* __restrict__ A,
                                                 const float* __restrict__ Bm,
                                                 float* __restrict__ C) {
  __shared__ float As[BK][BM + 8];
  __shared__ float Bs[BK][BN];
  const int tid = threadIdx.x;
  const int bx = blockIdx.x;  // N tile
  const int by = blockIdx.y;  // M tile
  const int tx = tid & 15, ty = tid >> 4;
  const int row0 = by * BM, col0 = bx * BN;

  float acc[8][8] = {};  // current K-panel chain
  float tot[8][8] = {};  // folded previous panels
  const float* Ab = A + (size_t)row0 * IN_D;
  const float* Bb = Bm + col0;

  for (int k0 = 0; k0 < IN_D; k0 += BK) {
    if (k0 == 288 || k0 == 576 || k0 == 864) {   // Eigen kc=288 panel folds
#pragma unroll
      for (int i = 0; i < 8; ++i)
#pragma unroll
        for (int j = 0; j < 8; ++j) { tot[i][j] = tot[i][j] + acc[i][j]; acc[i][j] = 0.f; }
    }
#pragma unroll
    for (int i = 0; i < 4; ++i) {
      int f = tid + i * 256;
      int m = f >> 3;
      int kc = (f & 7) << 2;
      float4 v = *(const float4*)(Ab + (size_t)m * IN_D + k0 + kc);
      As[kc + 0][m] = v.x; As[kc + 1][m] = v.y;
      As[kc + 2][m] = v.z; As[kc + 3][m] = v.w;
    }
#pragma unroll
    for (int i = 0; i < 4; ++i) {
      int f = tid + i * 256;
      int kr = f >> 5;
      int nc = (f & 31) << 2;
      *(float4*)(&Bs[kr][nc]) = *(const float4*)(Bb + (size_t)(k0 + kr) * CODE + nc);
    }
    __syncthreads();
#pragma unroll
    for (int kk = 0; kk < BK; ++kk) {
      float a[8], b[8];
      *(float4*)&a[0] = *(const float4*)&As[kk][ty * 8];
      *(float4*)&a[4] = *(const float4*)&As[kk][ty * 8 + 4];
      *(float4*)&b[0] = *(const float4*)&Bs[kk][tx * 8];
      *(float4*)&b[4] = *(const float4*)&Bs[kk][tx * 8 + 4];
#pragma unroll
      for (int i = 0; i < 8; ++i)
#pragma unroll
        for (int j = 0; j < 8; ++j) acc[i][j] = muladd(a[i], b[j], acc[i][j]);
    }
    __syncthreads();
  }
  float* Cb = C + (size_t)(row0 + ty * 8) * CODE + col0 + tx * 8;
#pragma unroll
  for (int i = 0; i < 8; ++i) {
    float4 o0, o1;
    o0.x = tot[i][0] + acc[i][0]; o0.y = tot[i][1] + acc[i][1];
    o0.z = tot[i][2] + acc[i][2]; o0.w = tot[i][3] + acc[i][3];
    o1.x = tot[i][4] + acc[i][4]; o1.y = tot[i][5] + acc[i][5];
    o1.z = tot[i][6] + acc[i][6]; o1.w = tot[i][7] + acc[i][7];
    *(float4*)(Cb + (size_t)i * CODE) = o0;
    *(float4*)(Cb + (size_t)i * CODE + 4) = o1;
  }
}

// ---------- fused t2 = f32 kc=288 mul+add chain z@S; u = t1+t2; stable top-64 ----------
__device__ __forceinline__ int waveReduceSum(int v) {
#pragma unroll
  for (int d = 32; d > 0; d >>= 1) v += __shfl_xor(v, d);
  return v;
}

__global__ __launch_bounds__(256) void k_layer_np(
    const float* __restrict__ S,
    float* __restrict__ zdense,          // t1 in / dense z out
    const int* __restrict__ cidx_in, const float* __restrict__ cval_in,
    int* __restrict__ cidx_out, float* __restrict__ cval_out,
    int hasZ, int writeDense) {
  const int row = blockIdx.x;
  const int tid = threadIdx.x;
  const int lane = tid & 63, wid = tid >> 6;

  __shared__ float s_val[TOPK];
  __shared__ int s_idx[TOPK];
  __shared__ int s_red[4];
  __shared__ int s_ncand;
  __shared__ int s_candcol[256];
  __shared__ unsigned s_bm[128];
  __shared__ int s_wtot[4][4];  // [j][wave]

  if (hasZ && tid < TOPK) {
    s_idx[tid] = cidx_in[(size_t)row * TOPK + tid];  // ascending columns
    s_val[tid] = cval_in[(size_t)row * TOPK + tid];
  }
  if (tid < 128) s_bm[tid] = 0;
  if (tid == 0) s_ncand = 0;
  __syncthreads();

  // t1 row: 16 floats/thread; col(i) = (i>>2)*1024 + tid*4 + (i&3)
  float t1[16];
  float* zr = zdense + (size_t)row * CODE;
#pragma unroll
  for (int j = 0; j < 4; ++j)
    *(float4*)&t1[j * 4] = *(const float4*)(zr + j * 1024 + tid * 4);

  float u[16];
  {
    float pacc[16], ptot[16];
#pragma unroll
    for (int i = 0; i < 16; ++i) { pacc[i] = 0.f; ptot[i] = 0.f; }
    if (hasZ) {
      int curp = -1;
      for (int t = 0; t < TOPK; ++t) {
        const int idx = s_idx[t];
        const float v = s_val[t];
        const int p = panel4096(idx);
        if (p != curp) {
          if (curp >= 0) {
#pragma unroll
            for (int i = 0; i < 16; ++i) { ptot[i] = ptot[i] + pacc[i]; pacc[i] = 0.f; }
          }
          curp = p;
        }
        const float* Sr = S + (size_t)idx * CODE;
#pragma unroll
        for (int j = 0; j < 4; ++j) {
          float4 sv = *(const float4*)(Sr + j * 1024 + tid * 4);
          pacc[j * 4 + 0] = muladd(v, sv.x, pacc[j * 4 + 0]);
          pacc[j * 4 + 1] = muladd(v, sv.y, pacc[j * 4 + 1]);
          pacc[j * 4 + 2] = muladd(v, sv.z, pacc[j * 4 + 2]);
          pacc[j * 4 + 3] = muladd(v, sv.w, pacc[j * 4 + 3]);
        }
      }
    }
#pragma unroll
    for (int i = 0; i < 16; ++i) {
      float t2 = ptot[i] + pacc[i];     // fold last panel
      u[i] = t1[i] + t2;                // u = t1 +f32 t2
    }
  }

  unsigned au[16];
#pragma unroll
  for (int i = 0; i < 16; ++i) au[i] = __float_as_uint(u[i]) & 0x7fffffffu;

  // binary search for V = 64th-largest f32 |u| bit pattern
  unsigned V = 0;
  for (int b = 30; b >= 0; --b) {
    unsigned T2 = V | (1u << b);
    int c = 0;
#pragma unroll
    for (int i = 0; i < 16; ++i) c += (au[i] >= T2) ? 1 : 0;
    c = waveReduceSum(c);
    if (lane == 0) s_red[wid] = c;
    __syncthreads();
    int tot = s_red[0] + s_red[1] + s_red[2] + s_red[3];
    if (tot >= TOPK) V = T2;
    __syncthreads();
  }

  int cg = 0;
#pragma unroll
  for (int i = 0; i < 16; ++i) cg += (au[i] > V) ? 1 : 0;
  cg = waveReduceSum(cg);
  if (lane == 0) s_red[wid] = cg;
  __syncthreads();
  const int nG = s_red[0] + s_red[1] + s_red[2] + s_red[3];
  const int need = TOPK - nG;

  // ties at V: pick `need` lowest columns (lax.top_k stable)
#pragma unroll
  for (int i = 0; i < 16; ++i) {
    if (au[i] == V) {
      int p = atomicAdd(&s_ncand, 1);
      if (p < 256) s_candcol[p] = (i >> 2) * 1024 + tid * 4 + (i & 3);
    }
  }
  __syncthreads();
  if (tid == 0) {
    int nE = s_ncand < 256 ? s_ncand : 256;
    int ns = need < nE ? need : nE;
    for (int r = 0; r < ns; ++r) {
      int mi = 0x7fffffff, mp = 0;
      for (int q = 0; q < nE; ++q) {
        int cc = s_candcol[q];
        if (cc >= 0 && cc < mi) { mi = cc; mp = q; }
      }
      s_bm[mi >> 5] |= (1u << (mi & 31));
      s_candcol[mp] = -1;
    }
  }
  __syncthreads();

  bool sel[16];
#pragma unroll
  for (int i = 0; i < 16; ++i) {
    int col = (i >> 2) * 1024 + tid * 4 + (i & 3);
    sel[i] = (au[i] > V) || ((s_bm[col >> 5] >> (col & 31)) & 1u);
  }

  // ---- compaction in ASCENDING column order: key = (j, tid, r) ----
  int cnt[4], inc[4];
#pragma unroll
  for (int j = 0; j < 4; ++j) {
    int c = 0;
#pragma unroll
    for (int r = 0; r < 4; ++r) c += sel[j * 4 + r] ? 1 : 0;
    cnt[j] = c;
    int v = c;
#pragma unroll
    for (int d = 1; d < 64; d <<= 1) {
      int t = __shfl_up(v, d);
      if (lane >= d) v += t;
    }
    inc[j] = v;
  }
  if (lane == 63) {
#pragma unroll
    for (int j = 0; j < 4; ++j) s_wtot[j][wid] = inc[j];
  }
  __syncthreads();
  int base[4];
  {
    int run = 0;
#pragma unroll
    for (int j = 0; j < 4; ++j) {
      int before = 0;
      for (int w = 0; w < 4; ++w)
        if (w < wid) before += s_wtot[j][w];
      base[j] = run + before + inc[j] - cnt[j];
      run += s_wtot[j][0] + s_wtot[j][1] + s_wtot[j][2] + s_wtot[j][3];
    }
  }
#pragma unroll
  for (int j = 0; j < 4; ++j) {
    int pos = base[j];
#pragma unroll
    for (int r = 0; r < 4; ++r) {
      int i = j * 4 + r;
      if (sel[i]) {
        cidx_out[(size_t)row * TOPK + pos] = j * 1024 + tid * 4 + r;
        cval_out[(size_t)row * TOPK + pos] = u[i];
        pos++;
      }
    }
  }

  if (writeDense) {
#pragma unroll
    for (int j = 0; j < 4; ++j) {
      float4 o;
      o.x = sel[j * 4 + 0] ? u[j * 4 + 0] : 0.f;
      o.y = sel[j * 4 + 1] ? u[j * 4 + 1] : 0.f;
      o.z = sel[j * 4 + 2] ? u[j * 4 + 2] : 0.f;
      o.w = sel[j * 4 + 3] ? u[j * 4 + 3] : 0.f;
      *(float4*)(zr + j * 1024 + tid * 4) = o;
    }
  }
}

// ---------- recon = z @ dictT, f32 kc=288 mul+add chains (K=4096) ----------
__global__ __launch_bounds__(256) void k_recon_np(const float* __restrict__ dictT,
                                                  const int* __restrict__ cidx,
                                                  const float* __restrict__ cval,
                                                  float* __restrict__ recon) {
  const int row = blockIdx.x;
  const int tid = threadIdx.x;
  __shared__ int s_idx[TOPK];
  __shared__ float s_val[TOPK];
  if (tid < TOPK) {
    s_idx[tid] = cidx[(size_t)row * TOPK + tid];  // ascending
    s_val[tid] = cval[(size_t)row * TOPK + tid];
  }
  __syncthreads();
  float pacc[4] = {0.f, 0.f, 0.f, 0.f};
  float ptot[4] = {0.f, 0.f, 0.f, 0.f};
  int curp = -1;
  for (int t = 0; t < TOPK; ++t) {
    const int idx = s_idx[t];
    const float v = s_val[t];
    const int p = panel4096(idx);
    if (p != curp) {
      if (curp >= 0) {
#pragma unroll
        for (int i = 0; i < 4; ++i) { ptot[i] = ptot[i] + pacc[i]; pacc[i] = 0.f; }
      }
      curp = p;
    }
    float4 d = *(const float4*)(dictT + (size_t)idx * IN_D + tid * 4);
    pacc[0] = muladd(v, d.x, pacc[0]);
    pacc[1] = muladd(v, d.y, pacc[1]);
    pacc[2] = muladd(v, d.z, pacc[2]);
    pacc[3] = muladd(v, d.w, pacc[3]);
  }
  float4 o;
  o.x = ptot[0] + pacc[0];
  o.y = ptot[1] + pacc[1];
  o.z = ptot[2] + pacc[2];
  o.w = ptot[3] + pacc[3];
  *(float4*)(recon + (size_t)row * IN_D + tid * 4) = o;
}

extern "C" void kernel_launch(void* const* d_in, const int* in_sizes, int n_in,
                              void* d_out, int out_size, void* d_ws, size_t ws_size,
                              hipStream_t stream) {
  const float* x = (const float*)d_in[0];
  const float* dict = (const float*)d_in[1];
  const float* Ws = (const float*)d_in[2];
  const float* Ss = (const float*)d_in[3];

  float* recon = (float*)d_out;
  float* zdense = recon + (size_t)B_ROWS * IN_D;  // t1/u scratch, final dense z

  char* w = (char*)d_ws;
  float* dictT = (float*)w;  w += (size_t)CODE * IN_D * 4;   // 16MB
  int* cidxA = (int*)w;      w += (size_t)B_ROWS * TOPK * 4;
  int* cidxB = (int*)w;      w += (size_t)B_ROWS * TOPK * 4;
  float* cvalA = (float*)w;  w += (size_t)B_ROWS * TOPK * 4;
  float* cvalB = (float*)w;

  k_transpose<<<dim3(CODE / 32, IN_D / 32), dim3(32, 8), 0, stream>>>(dict, dictT);

  int* ci_in = cidxA; float* cv_in = cvalA;
  int* ci_out = cidxB; float* cv_out = cvalB;

  for (int l = 0; l < LAYERS; ++l) {
    const float* W = Ws + (size_t)l * IN_D * CODE;
    const float* S = Ss + (size_t)l * CODE * CODE;
    k_gemm_np<<<dim3(CODE / BN, B_ROWS / BM), 256, 0, stream>>>(x, W, zdense);
    k_layer_np<<<B_ROWS, 256, 0, stream>>>(S, zdense, ci_in, cv_in, ci_out, cv_out,
                                           l > 0 ? 1 : 0, l == LAYERS - 1 ? 1 : 0);
    int* ti = ci_in; ci_in = ci_out; ci_out = ti;
    float* tv = cv_in; cv_in = cv_out; cv_out = tv;
  }
  k_recon_np<<<B_ROWS, 256, 0, stream>>>(dictT, ci_in, cv_in, recon);
}